// Round 18
// baseline (386.131 us; speedup 1.0000x reference)
//
#include <hip/hip_runtime.h>

typedef float  f32x4  __attribute__((ext_vector_type(4)));
typedef short  bf16x8 __attribute__((ext_vector_type(8)));
typedef unsigned short u16x4 __attribute__((ext_vector_type(4)));

typedef const __attribute__((address_space(1))) unsigned int* gas_u32;
typedef __attribute__((address_space(3))) unsigned int* las_u32;

#define MFMA16(a,b,c) __builtin_amdgcn_mfma_f32_16x16x32_bf16((a),(b),(c),0,0,0)

__device__ __forceinline__ unsigned short f2bf(float f){
  unsigned u = __float_as_uint(f);
  u += 0x7fffu + ((u>>16)&1u);            // RNE
  return (unsigned short)(u>>16);
}
__device__ __forceinline__ float bf2f(unsigned short u){
  return __uint_as_float(((unsigned)u)<<16);
}
__device__ __forceinline__ float sigm(float x){
  return __fdividef(1.f, 1.f + __expf(-x));
}
__device__ __forceinline__ float tanhfast(float x){
  return 1.f - __fdividef(2.f, __expf(2.f*x) + 1.f);
}
__device__ __forceinline__ float dot128(const float* __restrict__ w, const float* s){
  float a0=0.f,a1=0.f,a2=0.f,a3=0.f;
  #pragma unroll
  for (int e=0;e<32;++e){
    f32x4 w4 = *(const f32x4*)(w + (e<<2));
    f32x4 x4 = *(const f32x4*)(s + (e<<2));
    a0 = fmaf(w4[0],x4[0],a0); a1 = fmaf(w4[1],x4[1],a1);
    a2 = fmaf(w4[2],x4[2],a2); a3 = fmaf(w4[3],x4[3],a3);
  }
  return (a0+a1)+(a2+a3);
}
__device__ __forceinline__ bf16x8 cvt8(const f32x4 a, const f32x4 b){
  union { int i[4]; bf16x8 v; } u;
  asm("v_cvt_pk_bf16_f32 %0, %1, %2" : "=v"(u.i[0]) : "v"(a[0]), "v"(a[1]));
  asm("v_cvt_pk_bf16_f32 %0, %1, %2" : "=v"(u.i[1]) : "v"(a[2]), "v"(a[3]));
  asm("v_cvt_pk_bf16_f32 %0, %1, %2" : "=v"(u.i[2]) : "v"(b[0]), "v"(b[1]));
  asm("v_cvt_pk_bf16_f32 %0, %1, %2" : "=v"(u.i[3]) : "v"(b[2]), "v"(b[3]));
  return u.v;
}
__device__ __forceinline__ u16x4 pack4(float a, float b, float c, float d){
  union { int i[2]; u16x4 v; } u;
  asm("v_cvt_pk_bf16_f32 %0, %1, %2" : "=v"(u.i[0]) : "v"(a), "v"(b));
  asm("v_cvt_pk_bf16_f32 %0, %1, %2" : "=v"(u.i[1]) : "v"(c), "v"(d));
  return u.v;
}
// f32-tile element xor (16B granule) and seq bf16 element xor
__device__ __forceinline__ int swx(int m){ return (((m&7)<<1) | ((m>>3)&1)) << 2; }
__device__ __forceinline__ int sws(int m){ return ((m&7)<<3) | (((m>>3)&1)<<6); }

// LDS map (57856 B) — r9 champion + ring-4 (still 2 blocks/CU)
#define XB_OFF   0        // 4 ring bufs x 16 rows x 128 f32 (8192 B each) = 32768
#define SEQ_OFF  32768    // 64x128 bf16 = 16384
#define QKB_OFF  49152    // [4 src][2 head][128] bf16 = 2048
#define SC_OFF   51200    // [2][64] f32 = 512
#define SH_OFF   51712    // [4][2][128] f32 = 4096
#define BIAS_OFF 55808    // 4 x f32[128] = 2048
#define SMEM_SZ  57856

// =================== prep v2 (r17, ~47us): rebalanced, vectorized ===================
__global__ void prep_all(const float* __restrict__ wih, const float* __restrict__ whh,
                         const float* __restrict__ wqs, const float* __restrict__ wks,
                         const float* __restrict__ wvs, const float* __restrict__ fcw,
                         const float* __restrict__ src, const int* __restrict__ mask_i,
                         const float* __restrict__ hid,
                         unsigned short* __restrict__ wbf, float* __restrict__ M_ws,
                         unsigned short* __restrict__ qk_ws,
                         unsigned long long* __restrict__ mask_bits,
                         int* __restrict__ flags){
  __shared__ __align__(16) float sl_src[8*128];
  __shared__ __align__(16) float sl_q[8*128];
  const int b = blockIdx.x, t = threadIdx.x;
  if (b < 96){                        // weights -> bf16, 4 elems/thread
    const int q = b*256 + t;
    const int base = q<<2;
    f32x4 v;
    if (base < 49152) v = *(const f32x4*)(wih + base);
    else              v = *(const f32x4*)(whh + (base - 49152));
    *(u16x4*)&wbf[base] = pack4(v[0],v[1],v[2],v[3]);
  } else if (b < 128){                // M[h][d][e] = fc_w_h @ Wv_h, f32x4/thread
    const int q = (b-96)*256 + t;
    const int h = q>>12, d = (q>>5)&127, e4 = (q&31)<<2;
    f32x4 a = {0.f,0.f,0.f,0.f};
    for (int j=0;j<64;++j){
      const float w = fcw[d*128 + (h<<6) + j];
      const f32x4 v = *(const f32x4*)(wvs + ((h<<6)+j)*128 + e4);
      #pragma unroll
      for (int i=0;i<4;++i) a[i] = fmaf(w, v[i], a[i]);
    }
    *(f32x4*)&M_ws[(h<<14) + (d<<7) + e4] = a;
  } else if (b < 1152){               // qk = (1/8) * Wk_h^T (Wq_h src), 8 src/block
    const int blk = b - 128;
    const size_t s0 = (size_t)blk * 8;
    #pragma unroll
    for (int i=0;i<4;++i) sl_src[t + (i<<8)] = src[s0*128 + t + (i<<8)];
    __syncthreads();
    #pragma unroll
    for (int k=0;k<4;++k){
      const int job = t + (k<<8), s = job>>7, c = job&127;
      sl_q[job] = dot128(wqs + c*128, sl_src + s*128);
    }
    __syncthreads();
    const int d = t&127, h = (t>>7)&1;
    float acc[8];
    #pragma unroll
    for (int s=0;s<8;++s) acc[s]=0.f;
    for (int j=0;j<64;++j){
      const float wk = wks[((h<<6)+j)*128 + d];
      #pragma unroll
      for (int s=0;s<8;++s) acc[s] = fmaf(wk, sl_q[s*128 + (h<<6) + j], acc[s]);
    }
    #pragma unroll
    for (int s=0;s<8;++s) qk_ws[(s0+s)*256 + (h<<7) + d] = f2bf(acc[s]*0.125f);
  } else if (b < 3200){               // mask -> 64-bit masks (self-probing dtype)
    const int blk = b - 1152;
    const int wv = t>>6, lane = t&63;
    const int gsrc = blk*4 + wv;
    const unsigned v = (unsigned)mask_i[(size_t)gsrc*64 + lane];
    const int bytemode = __any((int)(v > 1u));
    bool bit;
    if (bytemode) bit = (((const unsigned char*)mask_i)[(size_t)gsrc*64 + lane] != 0);
    else          bit = (v != 0u);
    const unsigned long long bits = __ballot((int)bit);
    if (lane == 0) mask_bits[gsrc] = bits;
  } else {                            // hid zero scan: 4096 blocks x 64KB
    const size_t blk = b - 3200;
    bool nz = false;
    #pragma unroll 16
    for (int it=0; it<16; ++it){
      const size_t idx = blk*4096 + (size_t)(it<<8) + t;  // f32x4 units
      const f32x4 v = *(const f32x4*)(hid + idx*4);
      nz = nz || (v[0]!=0.f)||(v[1]!=0.f)||(v[2]!=0.f)||(v[3]!=0.f);
    }
    if (__ballot((int)nz)){ if ((t&63)==0) atomicOr(flags+1, 1); }
  }
}

// ---- attention tail: MFMA scores -> softmax -> PV (writes sH[srcI]) ----
__device__ __forceinline__ void scores_pv(char* smem, int srcI, unsigned long long mb,
                                          int wv, int lane, int l15, int lgrp){
  unsigned short* seq = (unsigned short*)(smem + SEQ_OFF);
  const unsigned short* qkb = (const unsigned short*)(smem + QKB_OFF);
  float* sc = (float*)(smem + SC_OFF);
  float* sH = (float*)(smem + SH_OFF);
  const f32x4 z4 = {0.f,0.f,0.f,0.f};
  {
    const int srow = (wv<<4) + l15;
    f32x4 s4 = z4;
    #pragma unroll
    for (int kb=0;kb<4;++kb){
      const int ko = (kb<<5) + (lgrp<<3);
      bf16x8 qa = *(const bf16x8*)&qkb[(srcI<<8) + ((l15&1)<<7) + ko];
      bf16x8 sb = *(const bf16x8*)&seq[(srow<<7) + (ko ^ sws(srow))];
      s4 = MFMA16(qa, sb, s4);
    }
    if (lgrp == 0){                      // C rows 0,1 = heads
      sc[      (wv<<4) + l15] = s4[0];
      sc[64 +  (wv<<4) + l15] = s4[1];
    }
  }
  asm volatile("s_waitcnt lgkmcnt(0)" ::: "memory");
  __builtin_amdgcn_sched_barrier(0);
  __builtin_amdgcn_s_barrier();
  if (wv < 2){
    float s = ((mb>>lane)&1ull) ? -1e10f : sc[(wv<<6)+lane];
    float mx = s;
    #pragma unroll
    for (int o=32;o>=1;o>>=1) mx = fmaxf(mx, __shfl_xor(mx,o));
    const float e = __expf(s - mx);
    float sum = e;
    #pragma unroll
    for (int o=32;o>=1;o>>=1) sum += __shfl_xor(sum,o);
    sc[(wv<<6)+lane] = __fdividef(e, sum);
  }
  asm volatile("s_waitcnt lgkmcnt(0)" ::: "memory");
  __builtin_amdgcn_sched_barrier(0);
  __builtin_amdgcn_s_barrier();
  {
    const int tt = (wv<<6) + lane;
    const int jidx = tt>>2, sub = tt&3;
    const int hh2 = jidx>>5, quad = jidx&31;
    f32x4 a = z4;
    #pragma unroll
    for (int i=0;i<16;++i){
      const int rr = (sub<<4)+i;
      const u16x4 sv = *(const u16x4*)&seq[(rr<<7) + ((quad<<2) ^ sws(rr))];
      const float w = sc[(hh2<<6)+rr];
      #pragma unroll
      for (int k=0;k<4;++k) a[k] = fmaf(w, bf2f(sv[k]), a[k]);
    }
    #pragma unroll
    for (int k=0;k<4;++k){ a[k] += __shfl_xor(a[k],1); a[k] += __shfl_xor(a[k],2); }
    if (sub == 0)
      *(f32x4*)&sH[(((srcI<<1)+hh2)<<7) + (quad<<2)] = a;
  }
}

// =================== main fused kernel: 4 sources / block ===================
// r9 champion + ring-4 depth-3 prefetch: issue(k+2) moved BEFORE the wait
// (buffer (k+2)&3 last read by stage k-2, drained one barrier ago), so 6 loads
// stay in flight across the stall; wait vmcnt(4) drains exactly stage k.
__global__ __attribute__((amdgpu_flat_work_group_size(256,256)))
           __attribute__((amdgpu_waves_per_eu(2)))
void cawn_main(
    const float* __restrict__ src, const float* __restrict__ ngh,
    const float* __restrict__ hid,
    const float* __restrict__ bih, const float* __restrict__ bhh,
    const float* __restrict__ fcb, const float* __restrict__ lng,
    const float* __restrict__ lnb, const float* __restrict__ m1w,
    const float* __restrict__ m1b, const float* __restrict__ m2w,
    const float* __restrict__ m2b,
    const unsigned short* __restrict__ wihb, const unsigned short* __restrict__ whhb,
    const float* __restrict__ M_ws, const unsigned short* __restrict__ qk_ws,
    const unsigned long long* __restrict__ mask_bits,
    const int* __restrict__ flags, float* __restrict__ out)
{
  __shared__ __align__(16) char smem[SMEM_SZ];
  float* brz0   = (float*)(smem + BIAS_OFF);
  float* brz1   = (float*)(smem + BIAS_OFF + 512);
  float* bin_l  = (float*)(smem + BIAS_OFF + 1024);
  float* bhn_l  = (float*)(smem + BIAS_OFF + 1536);
  unsigned short* seq = (unsigned short*)(smem + SEQ_OFF);
  unsigned short* qkb = (unsigned short*)(smem + QKB_OFF);

  const int t    = threadIdx.x;
  const int wv   = t >> 6;
  const int lane = t & 63;
  const int l15  = lane & 15;
  const int lgrp = lane >> 4;
  const int gsrc0 = blockIdx.x * 4;
  const f32x4 z4 = {0.f,0.f,0.f,0.f};
  const int hz = flags[1];

  if (t < 128){
    brz0[t]  = bih[t]     + bhh[t];
    brz1[t]  = bih[128+t] + bhh[128+t];
    bin_l[t] = bih[256+t];
    bhn_l[t] = bhh[256+t];
  }
  #pragma unroll
  for (int s=0;s<4;++s)
    qkb[(s<<8)+t] = qk_ws[(size_t)(gsrc0+s)*256 + t];
  const unsigned long long mb0 = mask_bits[gsrc0];
  const unsigned long long mb1 = mask_bits[gsrc0+1];
  const unsigned long long mb2 = mask_bits[gsrc0+2];
  const unsigned long long mb3 = mask_bits[gsrc0+3];

  if (!hz){
    // ---------------- FAST PATH: h == 0, ring-4 async pipeline ----------------
    bf16x8 Wf[3][2][4];     // W_ih stationary: wave wv owns cols [32wv,32wv+32)
    #pragma unroll
    for (int g=0; g<3; ++g)
      #pragma unroll
      for (int j=0; j<2; ++j){
        const int nc = (wv<<5) + (j<<4) + l15;
        #pragma unroll
        for (int kb=0; kb<4; ++kb)
          Wf[g][j][kb] = *(const bf16x8*)(wihb + (((g<<7) + nc)<<7) + (kb<<5) + (lgrp<<3));
      }

    auto issue = [&](int kk, int rbuf){
      const int srcI = kk>>2, stg = kk&3;
      const size_t base = (size_t)(gsrc0+srcI)*8192 + (size_t)stg*2048; // f32 units
      #pragma unroll
      for (int r=0;r<2;++r){
        const int rl = (wv<<2) + (r<<1) + (lane>>5);
        const int s16 = (lane&31) ^ (((rl&7)<<1) | ((rl>>3)&1));
        const float* g = ngh + base + (rl<<7) + (s16<<2);
        char* l = smem + XB_OFF + rbuf*8192 + (((wv<<2)+(r<<1))<<9);
        __builtin_amdgcn_global_load_lds((gas_u32)g, (las_u32)l, 16, 0, 0);
      }
    };
    issue(0,0); issue(1,1);

    for (int k=0;k<16;++k){
      if (k+2 < 16) issue(k+2, (k+2)&3);   // safe: stage k-2's readers drained a barrier ago
      if (k < 14)      asm volatile("s_waitcnt vmcnt(4) lgkmcnt(0)" ::: "memory");
      else if (k==14)  asm volatile("s_waitcnt vmcnt(2) lgkmcnt(0)" ::: "memory");
      else             asm volatile("s_waitcnt vmcnt(0) lgkmcnt(0)" ::: "memory");
      __builtin_amdgcn_sched_barrier(0);
      __builtin_amdgcn_s_barrier();

      const int srcI = k>>2, stg = k&3;
      const float* xrow = (const float*)(smem + XB_OFF + (k&3)*8192) + (l15<<7);
      const int sw = swx(l15);
      bf16x8 bx[4];
      #pragma unroll
      for (int kb=0;kb<4;++kb){
        const int c0 = (kb<<5) + (lgrp<<3);
        bx[kb] = cvt8(*(const f32x4*)&xrow[c0 ^ sw], *(const f32x4*)&xrow[(c0+4) ^ sw]);
      }
      f32x4 ar[2]={z4,z4}, az[2]={z4,z4}, an[2]={z4,z4};
      #pragma unroll
      for (int j=0;j<2;++j)
        #pragma unroll
        for (int kb=0;kb<4;++kb){
          ar[j] = MFMA16(Wf[0][j][kb], bx[kb], ar[j]);
          az[j] = MFMA16(Wf[1][j][kb], bx[kb], az[j]);
          an[j] = MFMA16(Wf[2][j][kb], bx[kb], an[j]);
        }
      const int mrow = (stg<<4) + l15;
      #pragma unroll
      for (int j=0;j<2;++j){
        const int colb = (wv<<5) + (j<<4) + (lgrp<<2);
        const f32x4 b0 = *(const f32x4*)&brz0[colb];
        const f32x4 b1 = *(const f32x4*)&brz1[colb];
        const f32x4 b2 = *(const f32x4*)&bin_l[colb];
        const f32x4 b3 = *(const f32x4*)&bhn_l[colb];
        float o[4];
        #pragma unroll
        for (int i=0;i<4;++i){
          const float rv = sigm(ar[j][i] + b0[i]);
          const float zv = sigm(az[j][i] + b1[i]);
          const float nv = tanhfast(an[j][i] + b2[i] + rv*b3[i]);
          o[i] = (1.f - zv)*nv;
        }
        *(u16x4*)&seq[(mrow<<7) + (colb ^ sws(mrow))] = pack4(o[0],o[1],o[2],o[3]);
      }

      if (stg == 3){
        asm volatile("s_waitcnt lgkmcnt(0)" ::: "memory");
        __builtin_amdgcn_sched_barrier(0);
        __builtin_amdgcn_s_barrier();
        const unsigned long long mb = (srcI==0)?mb0:(srcI==1)?mb1:(srcI==2)?mb2:mb3;
        scores_pv(smem, srcI, mb, wv, lane, l15, lgrp);
      }
    }
  } else {
    // ---------------- SLOW PATH (general h): correct, unpipelined ----------------
    float* xb0 = (float*)(smem + XB_OFF);
    float* xb1 = (float*)(smem + XB_OFF + 8192);
    for (int srcI=0;srcI<4;++srcI){
      const int gsrc = gsrc0+srcI;
      for (int stg=0;stg<4;++stg){
        #pragma unroll
        for (int it=0; it<2; ++it){
          const int f = t + (it<<8);
          const int m = f>>5, c0 = (f&31)<<2;
          const int sw = swx(m);
          const size_t gb = (size_t)gsrc*8192 + stg*2048 + (m<<7) + c0;
          *(f32x4*)&xb0[(m<<7)+(c0^sw)] = *(const f32x4*)(ngh+gb);
          *(f32x4*)&xb1[(m<<7)+(c0^sw)] = *(const f32x4*)(hid+gb);
        }
        __syncthreads();
        const float* xrow = xb0 + (l15<<7);
        const float* hrow = xb1 + (l15<<7);
        const int sw = swx(l15);
        bf16x8 bx[4], bh[4];
        #pragma unroll
        for (int kb=0;kb<4;++kb){
          const int c0 = (kb<<5) + (lgrp<<3);
          bx[kb] = cvt8(*(const f32x4*)&xrow[c0 ^ sw], *(const f32x4*)&xrow[(c0+4) ^ sw]);
          bh[kb] = cvt8(*(const f32x4*)&hrow[c0 ^ sw], *(const f32x4*)&hrow[(c0+4) ^ sw]);
        }
        f32x4 ar[2]={z4,z4}, az[2]={z4,z4}, an[2]={z4,z4}, anh[2]={z4,z4};
        #pragma unroll
        for (int j=0;j<2;++j){
          const int nc = (wv<<5)+(j<<4)+l15;
          #pragma unroll
          for (int kb=0;kb<4;++kb){
            const int ko=(kb<<5)+(lgrp<<3);
            ar[j]  = MFMA16(*(const bf16x8*)(wihb + ((      nc)<<7) + ko), bx[kb], ar[j]);
            az[j]  = MFMA16(*(const bf16x8*)(wihb + (((128)+nc)<<7) + ko), bx[kb], az[j]);
            an[j]  = MFMA16(*(const bf16x8*)(wihb + (((256)+nc)<<7) + ko), bx[kb], an[j]);
            ar[j]  = MFMA16(*(const bf16x8*)(whhb + ((      nc)<<7) + ko), bh[kb], ar[j]);
            az[j]  = MFMA16(*(const bf16x8*)(whhb + (((128)+nc)<<7) + ko), bh[kb], az[j]);
            anh[j] = MFMA16(*(const bf16x8*)(whhb + (((256)+nc)<<7) + ko), bh[kb], anh[j]);
          }
        }
        const int mrow = (stg<<4) + l15;
        #pragma unroll
        for (int j=0;j<2;++j){
          const int colb = (wv<<5) + (j<<4) + (lgrp<<2);
          const f32x4 b0 = *(const f32x4*)&brz0[colb];
          const f32x4 b1 = *(const f32x4*)&brz1[colb];
          const f32x4 b2 = *(const f32x4*)&bin_l[colb];
          const f32x4 b3 = *(const f32x4*)&bhn_l[colb];
          const f32x4 hv = *(const f32x4*)&hrow[colb ^ sw];
          float o[4];
          #pragma unroll
          for (int i=0;i<4;++i){
            const float rv = sigm(ar[j][i] + b0[i]);
            const float zv = sigm(az[j][i] + b1[i]);
            const float nv = tanhfast(an[j][i] + b2[i] + rv*(anh[j][i] + b3[i]));
            o[i] = (1.f - zv)*nv + zv*hv[i];
          }
          *(u16x4*)&seq[(mrow<<7) + (colb ^ sws(mrow))] = pack4(o[0],o[1],o[2],o[3]);
        }
        __syncthreads();
      }
      const unsigned long long mb = (srcI==0)?mb0:(srcI==1)?mb1:(srcI==2)?mb2:mb3;
      scores_pv(smem, srcI, mb, wv, lane, l15, lgrp);
      __syncthreads();
    }
  }

  // ---------------- epilogue: M-matvec + res + LN + merge MLP ----------------
  __syncthreads();
  float* ep1  = (float*)smem;            // [4][128]
  float* ep2  = (float*)(smem + 2048);   // [4][128]
  float* srce = (float*)(smem + 4096);   // [4][128]
  float* sH   = (float*)(smem + SH_OFF);
  srce[t]     = src[(size_t)gsrc0*128 + t];
  srce[t+256] = src[(size_t)gsrc0*128 + t + 256];
  __syncthreads();

  const int d  = t & 127;
  const int sh = (t >> 7) << 1;
  #pragma unroll
  for (int si=0; si<2; ++si){
    const int s = sh + si;
    float a = fcb[d];
    a += dot128(M_ws +         d*128, &sH[((s<<1)  )<<7]);
    a += dot128(M_ws + 16384 + d*128, &sH[((s<<1)+1)<<7]);
    ep1[s*128+d] = a + srce[s*128+d];
  }
  __syncthreads();
  {
    const int s = wv;
    const float v0 = ep1[s*128+lane], v1 = ep1[s*128+64+lane];
    float sum = v0+v1, sq_ = v0*v0 + v1*v1;
    #pragma unroll
    for (int o=32;o>=1;o>>=1){ sum += __shfl_xor(sum,o); sq_ += __shfl_xor(sq_,o); }
    const float mu  = sum * 0.0078125f;
    const float var = sq_ * 0.0078125f - mu*mu;
    const float rs  = rsqrtf(var + 1e-5f);
    ep1[s*128+lane]    = (v0-mu)*rs*lng[lane]    + lnb[lane];
    ep1[s*128+64+lane] = (v1-mu)*rs*lng[64+lane] + lnb[64+lane];
  }
  __syncthreads();
  #pragma unroll
  for (int si=0; si<2; ++si){
    const int s = sh + si;
    float a = m1b[d];
    a += dot128(m1w + d*256,       ep1  + s*128);
    a += dot128(m1w + d*256 + 128, srce + s*128);
    ep2[s*128+d] = fmaxf(a, 0.f);
  }
  __syncthreads();
  #pragma unroll
  for (int si=0; si<2; ++si){
    const int s = sh + si;
    out[(size_t)(gsrc0+s)*128 + d] = m2b[d] + dot128(m2w + d*128, ep2 + s*128);
  }
}

extern "C" void kernel_launch(void* const* d_in, const int* in_sizes, int n_in,
                              void* d_out, int out_size, void* d_ws, size_t ws_size,
                              hipStream_t stream){
  const float* src = (const float*)d_in[0];
  const float* ngh = (const float*)d_in[1];
  const float* hid = (const float*)d_in[2];
  const int*   msk = (const int*)  d_in[3];
  const float* wih = (const float*)d_in[4];
  const float* whh = (const float*)d_in[5];
  const float* bih = (const float*)d_in[6];
  const float* bhh = (const float*)d_in[7];
  const float* wqs = (const float*)d_in[8];
  const float* wks = (const float*)d_in[9];
  const float* wvs = (const float*)d_in[10];
  const float* fcw = (const float*)d_in[11];
  const float* fcb = (const float*)d_in[12];
  const float* lng = (const float*)d_in[13];
  const float* lnb = (const float*)d_in[14];
  const float* m1w = (const float*)d_in[15];
  const float* m1b = (const float*)d_in[16];
  const float* m2w = (const float*)d_in[17];
  const float* m2b = (const float*)d_in[18];
  float* out = (float*)d_out;

  unsigned short* wbf   = (unsigned short*)d_ws;                   // 196608 B
  int*            flags = (int*)((char*)d_ws + 196608);            // 64 B
  float*          M_ws  = (float*)((char*)d_ws + 196672);          // 131072 B
  unsigned short* qk_ws = (unsigned short*)((char*)d_ws + 327744); // 4 MB
  unsigned long long* mask_bits = (unsigned long long*)((char*)d_ws + 4522048); // 64 KB

  hipMemsetAsync((char*)d_ws + 196608, 0, 64, stream);
  prep_all <<<7296, 256, 0, stream>>>(wih, whh, wqs, wks, wvs, fcw, src, msk, hid,
                                      wbf, M_ws, qk_ws, mask_bits, flags);
  cawn_main<<<2048, 256, 0, stream>>>(src, ngh, hid, bih, bhh,
                                      fcb, lng, lnb, m1w, m1b, m2w, m2b,
                                      wbf, wbf + 49152, M_ws, qk_ws,
                                      mask_bits, flags, out);
}

// Round 19
// 380.950 us; speedup vs baseline: 1.0136x; 1.0136x over previous
//
#include <hip/hip_runtime.h>

typedef float  f32x4  __attribute__((ext_vector_type(4)));
typedef short  bf16x8 __attribute__((ext_vector_type(8)));
typedef unsigned short u16x4 __attribute__((ext_vector_type(4)));

typedef const __attribute__((address_space(1))) unsigned int* gas_u32;
typedef __attribute__((address_space(3))) unsigned int* las_u32;

#define MFMA16(a,b,c) __builtin_amdgcn_mfma_f32_16x16x32_bf16((a),(b),(c),0,0,0)

__device__ __forceinline__ unsigned short f2bf(float f){
  unsigned u = __float_as_uint(f);
  u += 0x7fffu + ((u>>16)&1u);            // RNE
  return (unsigned short)(u>>16);
}
__device__ __forceinline__ float bf2f(unsigned short u){
  return __uint_as_float(((unsigned)u)<<16);
}
__device__ __forceinline__ float sigm(float x){
  return __fdividef(1.f, 1.f + __expf(-x));
}
__device__ __forceinline__ float tanhfast(float x){
  return 1.f - __fdividef(2.f, __expf(2.f*x) + 1.f);
}
__device__ __forceinline__ float dot128(const float* __restrict__ w, const float* s){
  float a0=0.f,a1=0.f,a2=0.f,a3=0.f;
  #pragma unroll
  for (int e=0;e<32;++e){
    f32x4 w4 = *(const f32x4*)(w + (e<<2));
    f32x4 x4 = *(const f32x4*)(s + (e<<2));
    a0 = fmaf(w4[0],x4[0],a0); a1 = fmaf(w4[1],x4[1],a1);
    a2 = fmaf(w4[2],x4[2],a2); a3 = fmaf(w4[3],x4[3],a3);
  }
  return (a0+a1)+(a2+a3);
}
__device__ __forceinline__ bf16x8 cvt8(const f32x4 a, const f32x4 b){
  union { int i[4]; bf16x8 v; } u;
  asm("v_cvt_pk_bf16_f32 %0, %1, %2" : "=v"(u.i[0]) : "v"(a[0]), "v"(a[1]));
  asm("v_cvt_pk_bf16_f32 %0, %1, %2" : "=v"(u.i[1]) : "v"(a[2]), "v"(a[3]));
  asm("v_cvt_pk_bf16_f32 %0, %1, %2" : "=v"(u.i[2]) : "v"(b[0]), "v"(b[1]));
  asm("v_cvt_pk_bf16_f32 %0, %1, %2" : "=v"(u.i[3]) : "v"(b[2]), "v"(b[3]));
  return u.v;
}
__device__ __forceinline__ u16x4 pack4(float a, float b, float c, float d){
  union { int i[2]; u16x4 v; } u;
  asm("v_cvt_pk_bf16_f32 %0, %1, %2" : "=v"(u.i[0]) : "v"(a), "v"(b));
  asm("v_cvt_pk_bf16_f32 %0, %1, %2" : "=v"(u.i[1]) : "v"(c), "v"(d));
  return u.v;
}
// f32-tile element xor (16B granule) and seq bf16 element xor
__device__ __forceinline__ int swx(int m){ return (((m&7)<<1) | ((m>>3)&1)) << 2; }
__device__ __forceinline__ int sws(int m){ return ((m&7)<<3) | (((m>>3)&1)<<6); }

// LDS map (49664 B) — r9 champion layout
#define XB_OFF   0        // 3 ring bufs x 16 rows x 128 f32 (8192 B each) = 24576
#define SEQ_OFF  24576    // 64x128 bf16 = 16384
#define QKB_OFF  40960    // [4 src][2 head][128] bf16 = 2048
#define SC_OFF   43008    // [2][64] f32 = 512
#define SH_OFF   43520    // [4][2][128] f32 = 4096
#define BIAS_OFF 47616    // 4 x f32[128] = 2048
#define SMEM_SZ  49664

// =================== prep v2 (r17, ~47us): rebalanced, vectorized ===================
__global__ void prep_all(const float* __restrict__ wih, const float* __restrict__ whh,
                         const float* __restrict__ wqs, const float* __restrict__ wks,
                         const float* __restrict__ wvs, const float* __restrict__ fcw,
                         const float* __restrict__ src, const int* __restrict__ mask_i,
                         const float* __restrict__ hid,
                         unsigned short* __restrict__ wbf, float* __restrict__ M_ws,
                         unsigned short* __restrict__ qk_ws,
                         unsigned long long* __restrict__ mask_bits,
                         int* __restrict__ flags){
  __shared__ __align__(16) float sl_src[8*128];
  __shared__ __align__(16) float sl_q[8*128];
  const int b = blockIdx.x, t = threadIdx.x;
  if (b < 96){                        // weights -> bf16, 4 elems/thread
    const int q = b*256 + t;
    const int base = q<<2;
    f32x4 v;
    if (base < 49152) v = *(const f32x4*)(wih + base);
    else              v = *(const f32x4*)(whh + (base - 49152));
    *(u16x4*)&wbf[base] = pack4(v[0],v[1],v[2],v[3]);
  } else if (b < 128){                // M[h][d][e] = fc_w_h @ Wv_h, f32x4/thread
    const int q = (b-96)*256 + t;
    const int h = q>>12, d = (q>>5)&127, e4 = (q&31)<<2;
    f32x4 a = {0.f,0.f,0.f,0.f};
    for (int j=0;j<64;++j){
      const float w = fcw[d*128 + (h<<6) + j];
      const f32x4 v = *(const f32x4*)(wvs + ((h<<6)+j)*128 + e4);
      #pragma unroll
      for (int i=0;i<4;++i) a[i] = fmaf(w, v[i], a[i]);
    }
    *(f32x4*)&M_ws[(h<<14) + (d<<7) + e4] = a;
  } else if (b < 1152){               // qk = (1/8) * Wk_h^T (Wq_h src), 8 src/block
    const int blk = b - 128;
    const size_t s0 = (size_t)blk * 8;
    #pragma unroll
    for (int i=0;i<4;++i) sl_src[t + (i<<8)] = src[s0*128 + t + (i<<8)];
    __syncthreads();
    #pragma unroll
    for (int k=0;k<4;++k){
      const int job = t + (k<<8), s = job>>7, c = job&127;
      sl_q[job] = dot128(wqs + c*128, sl_src + s*128);
    }
    __syncthreads();
    const int d = t&127, h = (t>>7)&1;
    float acc[8];
    #pragma unroll
    for (int s=0;s<8;++s) acc[s]=0.f;
    for (int j=0;j<64;++j){
      const float wk = wks[((h<<6)+j)*128 + d];
      #pragma unroll
      for (int s=0;s<8;++s) acc[s] = fmaf(wk, sl_q[s*128 + (h<<6) + j], acc[s]);
    }
    #pragma unroll
    for (int s=0;s<8;++s) qk_ws[(s0+s)*256 + (h<<7) + d] = f2bf(acc[s]*0.125f);
  } else if (b < 3200){               // mask -> 64-bit masks (self-probing dtype)
    const int blk = b - 1152;
    const int wv = t>>6, lane = t&63;
    const int gsrc = blk*4 + wv;
    const unsigned v = (unsigned)mask_i[(size_t)gsrc*64 + lane];
    const int bytemode = __any((int)(v > 1u));
    bool bit;
    if (bytemode) bit = (((const unsigned char*)mask_i)[(size_t)gsrc*64 + lane] != 0);
    else          bit = (v != 0u);
    const unsigned long long bits = __ballot((int)bit);
    if (lane == 0) mask_bits[gsrc] = bits;
  } else {                            // hid zero scan: 4096 blocks x 64KB
    const size_t blk = b - 3200;
    bool nz = false;
    #pragma unroll 16
    for (int it=0; it<16; ++it){
      const size_t idx = blk*4096 + (size_t)(it<<8) + t;  // f32x4 units
      const f32x4 v = *(const f32x4*)(hid + idx*4);
      nz = nz || (v[0]!=0.f)||(v[1]!=0.f)||(v[2]!=0.f)||(v[3]!=0.f);
    }
    if (__ballot((int)nz)){ if ((t&63)==0) atomicOr(flags+1, 1); }
  }
}

// ---- attention tail: MFMA scores -> softmax -> PV (writes sH[srcI]) ----
__device__ __forceinline__ void scores_pv(char* smem, int srcI, unsigned long long mb,
                                          int wv, int lane, int l15, int lgrp){
  unsigned short* seq = (unsigned short*)(smem + SEQ_OFF);
  const unsigned short* qkb = (const unsigned short*)(smem + QKB_OFF);
  float* sc = (float*)(smem + SC_OFF);
  float* sH = (float*)(smem + SH_OFF);
  const f32x4 z4 = {0.f,0.f,0.f,0.f};
  {
    const int srow = (wv<<4) + l15;
    f32x4 s4 = z4;
    #pragma unroll
    for (int kb=0;kb<4;++kb){
      const int ko = (kb<<5) + (lgrp<<3);
      bf16x8 qa = *(const bf16x8*)&qkb[(srcI<<8) + ((l15&1)<<7) + ko];
      bf16x8 sb = *(const bf16x8*)&seq[(srow<<7) + (ko ^ sws(srow))];
      s4 = MFMA16(qa, sb, s4);
    }
    if (lgrp == 0){                      // C rows 0,1 = heads
      sc[      (wv<<4) + l15] = s4[0];
      sc[64 +  (wv<<4) + l15] = s4[1];
    }
  }
  asm volatile("s_waitcnt lgkmcnt(0)" ::: "memory");
  __builtin_amdgcn_sched_barrier(0);
  __builtin_amdgcn_s_barrier();
  if (wv < 2){
    float s = ((mb>>lane)&1ull) ? -1e10f : sc[(wv<<6)+lane];
    float mx = s;
    #pragma unroll
    for (int o=32;o>=1;o>>=1) mx = fmaxf(mx, __shfl_xor(mx,o));
    const float e = __expf(s - mx);
    float sum = e;
    #pragma unroll
    for (int o=32;o>=1;o>>=1) sum += __shfl_xor(sum,o);
    sc[(wv<<6)+lane] = __fdividef(e, sum);
  }
  asm volatile("s_waitcnt lgkmcnt(0)" ::: "memory");
  __builtin_amdgcn_sched_barrier(0);
  __builtin_amdgcn_s_barrier();
  {
    const int tt = (wv<<6) + lane;
    const int jidx = tt>>2, sub = tt&3;
    const int hh2 = jidx>>5, quad = jidx&31;
    f32x4 a = z4;
    #pragma unroll
    for (int i=0;i<16;++i){
      const int rr = (sub<<4)+i;
      const u16x4 sv = *(const u16x4*)&seq[(rr<<7) + ((quad<<2) ^ sws(rr))];
      const float w = sc[(hh2<<6)+rr];
      #pragma unroll
      for (int k=0;k<4;++k) a[k] = fmaf(w, bf2f(sv[k]), a[k]);
    }
    #pragma unroll
    for (int k=0;k<4;++k){ a[k] += __shfl_xor(a[k],1); a[k] += __shfl_xor(a[k],2); }
    if (sub == 0)
      *(f32x4*)&sH[(((srcI<<1)+hh2)<<7) + (quad<<2)] = a;
  }
}

// =================== main fused kernel: 4 sources / block ===================
// r9 champion verbatim (333 us): waves_per_eu(2) -> VGPR 128, Wf resident,
// ring-3 global_load_lds pipeline with counted vmcnt(2). FROZEN.
__global__ __attribute__((amdgpu_flat_work_group_size(256,256)))
           __attribute__((amdgpu_waves_per_eu(2)))
void cawn_main(
    const float* __restrict__ src, const float* __restrict__ ngh,
    const float* __restrict__ hid,
    const float* __restrict__ bih, const float* __restrict__ bhh,
    const float* __restrict__ fcb, const float* __restrict__ lng,
    const float* __restrict__ lnb, const float* __restrict__ m1w,
    const float* __restrict__ m1b, const float* __restrict__ m2w,
    const float* __restrict__ m2b,
    const unsigned short* __restrict__ wihb, const unsigned short* __restrict__ whhb,
    const float* __restrict__ M_ws, const unsigned short* __restrict__ qk_ws,
    const unsigned long long* __restrict__ mask_bits,
    const int* __restrict__ flags, float* __restrict__ out)
{
  __shared__ __align__(16) char smem[SMEM_SZ];
  float* brz0   = (float*)(smem + BIAS_OFF);
  float* brz1   = (float*)(smem + BIAS_OFF + 512);
  float* bin_l  = (float*)(smem + BIAS_OFF + 1024);
  float* bhn_l  = (float*)(smem + BIAS_OFF + 1536);
  unsigned short* seq = (unsigned short*)(smem + SEQ_OFF);
  unsigned short* qkb = (unsigned short*)(smem + QKB_OFF);

  const int t    = threadIdx.x;
  const int wv   = t >> 6;
  const int lane = t & 63;
  const int l15  = lane & 15;
  const int lgrp = lane >> 4;
  const int gsrc0 = blockIdx.x * 4;
  const f32x4 z4 = {0.f,0.f,0.f,0.f};
  const int hz = flags[1];

  if (t < 128){
    brz0[t]  = bih[t]     + bhh[t];
    brz1[t]  = bih[128+t] + bhh[128+t];
    bin_l[t] = bih[256+t];
    bhn_l[t] = bhh[256+t];
  }
  #pragma unroll
  for (int s=0;s<4;++s)
    qkb[(s<<8)+t] = qk_ws[(size_t)(gsrc0+s)*256 + t];
  const unsigned long long mb0 = mask_bits[gsrc0];
  const unsigned long long mb1 = mask_bits[gsrc0+1];
  const unsigned long long mb2 = mask_bits[gsrc0+2];
  const unsigned long long mb3 = mask_bits[gsrc0+3];

  if (!hz){
    // ---------------- FAST PATH: h == 0, ring-3 async pipeline ----------------
    bf16x8 Wf[3][2][4];     // W_ih stationary: wave wv owns cols [32wv,32wv+32)
    #pragma unroll
    for (int g=0; g<3; ++g)
      #pragma unroll
      for (int j=0; j<2; ++j){
        const int nc = (wv<<5) + (j<<4) + l15;
        #pragma unroll
        for (int kb=0; kb<4; ++kb)
          Wf[g][j][kb] = *(const bf16x8*)(wihb + (((g<<7) + nc)<<7) + (kb<<5) + (lgrp<<3));
      }

    auto issue = [&](int kk, int rbuf){
      const int srcI = kk>>2, stg = kk&3;
      const size_t base = (size_t)(gsrc0+srcI)*8192 + (size_t)stg*2048; // f32 units
      #pragma unroll
      for (int r=0;r<2;++r){
        const int rl = (wv<<2) + (r<<1) + (lane>>5);
        const int s16 = (lane&31) ^ (((rl&7)<<1) | ((rl>>3)&1));
        const float* g = ngh + base + (rl<<7) + (s16<<2);
        char* l = smem + XB_OFF + rbuf*8192 + (((wv<<2)+(r<<1))<<9);
        __builtin_amdgcn_global_load_lds((gas_u32)g, (las_u32)l, 16, 0, 0);
      }
    };
    issue(0,0); issue(1,1);

    int rb = 0;
    for (int k=0;k<16;++k){
      if (k < 15) asm volatile("s_waitcnt vmcnt(2) lgkmcnt(0)" ::: "memory");
      else        asm volatile("s_waitcnt vmcnt(0) lgkmcnt(0)" ::: "memory");
      __builtin_amdgcn_sched_barrier(0);
      __builtin_amdgcn_s_barrier();
      if (k+2 < 16){                       // safe: all reads of this buf drained above
        int ri = rb+2; if (ri>=3) ri-=3;
        issue(k+2, ri);
      }

      const int srcI = k>>2, stg = k&3;
      const float* xrow = (const float*)(smem + XB_OFF + rb*8192) + (l15<<7);
      const int sw = swx(l15);
      bf16x8 bx[4];
      #pragma unroll
      for (int kb=0;kb<4;++kb){
        const int c0 = (kb<<5) + (lgrp<<3);
        bx[kb] = cvt8(*(const f32x4*)&xrow[c0 ^ sw], *(const f32x4*)&xrow[(c0+4) ^ sw]);
      }
      f32x4 ar[2]={z4,z4}, az[2]={z4,z4}, an[2]={z4,z4};
      #pragma unroll
      for (int j=0;j<2;++j)
        #pragma unroll
        for (int kb=0;kb<4;++kb){
          ar[j] = MFMA16(Wf[0][j][kb], bx[kb], ar[j]);
          az[j] = MFMA16(Wf[1][j][kb], bx[kb], az[j]);
          an[j] = MFMA16(Wf[2][j][kb], bx[kb], an[j]);
        }
      const int mrow = (stg<<4) + l15;
      #pragma unroll
      for (int j=0;j<2;++j){
        const int colb = (wv<<5) + (j<<4) + (lgrp<<2);
        const f32x4 b0 = *(const f32x4*)&brz0[colb];
        const f32x4 b1 = *(const f32x4*)&brz1[colb];
        const f32x4 b2 = *(const f32x4*)&bin_l[colb];
        const f32x4 b3 = *(const f32x4*)&bhn_l[colb];
        float o[4];
        #pragma unroll
        for (int i=0;i<4;++i){
          const float rv = sigm(ar[j][i] + b0[i]);
          const float zv = sigm(az[j][i] + b1[i]);
          const float nv = tanhfast(an[j][i] + b2[i] + rv*b3[i]);
          o[i] = (1.f - zv)*nv;
        }
        *(u16x4*)&seq[(mrow<<7) + (colb ^ sws(mrow))] = pack4(o[0],o[1],o[2],o[3]);
      }

      if (stg == 3){
        asm volatile("s_waitcnt lgkmcnt(0)" ::: "memory");
        __builtin_amdgcn_sched_barrier(0);
        __builtin_amdgcn_s_barrier();
        const unsigned long long mb = (srcI==0)?mb0:(srcI==1)?mb1:(srcI==2)?mb2:mb3;
        scores_pv(smem, srcI, mb, wv, lane, l15, lgrp);
      }
      rb = (rb+1 == 3) ? 0 : rb+1;
    }
  } else {
    // ---------------- SLOW PATH (general h): correct, unpipelined ----------------
    float* xb0 = (float*)(smem + XB_OFF);
    float* xb1 = (float*)(smem + XB_OFF + 8192);
    for (int srcI=0;srcI<4;++srcI){
      const int gsrc = gsrc0+srcI;
      for (int stg=0;stg<4;++stg){
        #pragma unroll
        for (int it=0; it<2; ++it){
          const int f = t + (it<<8);
          const int m = f>>5, c0 = (f&31)<<2;
          const int sw = swx(m);
          const size_t gb = (size_t)gsrc*8192 + stg*2048 + (m<<7) + c0;
          *(f32x4*)&xb0[(m<<7)+(c0^sw)] = *(const f32x4*)(ngh+gb);
          *(f32x4*)&xb1[(m<<7)+(c0^sw)] = *(const f32x4*)(hid+gb);
        }
        __syncthreads();
        const float* xrow = xb0 + (l15<<7);
        const float* hrow = xb1 + (l15<<7);
        const int sw = swx(l15);
        bf16x8 bx[4], bh[4];
        #pragma unroll
        for (int kb=0;kb<4;++kb){
          const int c0 = (kb<<5) + (lgrp<<3);
          bx[kb] = cvt8(*(const f32x4*)&xrow[c0 ^ sw], *(const f32x4*)&xrow[(c0+4) ^ sw]);
          bh[kb] = cvt8(*(const f32x4*)&hrow[c0 ^ sw], *(const f32x4*)&hrow[(c0+4) ^ sw]);
        }
        f32x4 ar[2]={z4,z4}, az[2]={z4,z4}, an[2]={z4,z4}, anh[2]={z4,z4};
        #pragma unroll
        for (int j=0;j<2;++j){
          const int nc = (wv<<5)+(j<<4)+l15;
          #pragma unroll
          for (int kb=0;kb<4;++kb){
            const int ko=(kb<<5)+(lgrp<<3);
            ar[j]  = MFMA16(*(const bf16x8*)(wihb + ((      nc)<<7) + ko), bx[kb], ar[j]);
            az[j]  = MFMA16(*(const bf16x8*)(wihb + (((128)+nc)<<7) + ko), bx[kb], az[j]);
            an[j]  = MFMA16(*(const bf16x8*)(wihb + (((256)+nc)<<7) + ko), bx[kb], an[j]);
            ar[j]  = MFMA16(*(const bf16x8*)(whhb + ((      nc)<<7) + ko), bh[kb], ar[j]);
            az[j]  = MFMA16(*(const bf16x8*)(whhb + (((128)+nc)<<7) + ko), bh[kb], az[j]);
            anh[j] = MFMA16(*(const bf16x8*)(whhb + (((256)+nc)<<7) + ko), bh[kb], anh[j]);
          }
        }
        const int mrow = (stg<<4) + l15;
        #pragma unroll
        for (int j=0;j<2;++j){
          const int colb = (wv<<5) + (j<<4) + (lgrp<<2);
          const f32x4 b0 = *(const f32x4*)&brz0[colb];
          const f32x4 b1 = *(const f32x4*)&brz1[colb];
          const f32x4 b2 = *(const f32x4*)&bin_l[colb];
          const f32x4 b3 = *(const f32x4*)&bhn_l[colb];
          const f32x4 hv = *(const f32x4*)&hrow[colb ^ sw];
          float o[4];
          #pragma unroll
          for (int i=0;i<4;++i){
            const float rv = sigm(ar[j][i] + b0[i]);
            const float zv = sigm(az[j][i] + b1[i]);
            const float nv = tanhfast(an[j][i] + b2[i] + rv*(anh[j][i] + b3[i]));
            o[i] = (1.f - zv)*nv + zv*hv[i];
          }
          *(u16x4*)&seq[(mrow<<7) + (colb ^ sws(mrow))] = pack4(o[0],o[1],o[2],o[3]);
        }
        __syncthreads();
      }
      const unsigned long long mb = (srcI==0)?mb0:(srcI==1)?mb1:(srcI==2)?mb2:mb3;
      scores_pv(smem, srcI, mb, wv, lane, l15, lgrp);
      __syncthreads();
    }
  }

  // ---------------- epilogue: M-matvec + res + LN + merge MLP ----------------
  __syncthreads();
  float* ep1  = (float*)smem;            // [4][128]
  float* ep2  = (float*)(smem + 2048);   // [4][128]
  float* srce = (float*)(smem + 4096);   // [4][128]
  float* sH   = (float*)(smem + SH_OFF);
  srce[t]     = src[(size_t)gsrc0*128 + t];
  srce[t+256] = src[(size_t)gsrc0*128 + t + 256];
  __syncthreads();

  const int d  = t & 127;
  const int sh = (t >> 7) << 1;
  #pragma unroll
  for (int si=0; si<2; ++si){
    const int s = sh + si;
    float a = fcb[d];
    a += dot128(M_ws +         d*128, &sH[((s<<1)  )<<7]);
    a += dot128(M_ws + 16384 + d*128, &sH[((s<<1)+1)<<7]);
    ep1[s*128+d] = a + srce[s*128+d];
  }
  __syncthreads();
  {
    const int s = wv;
    const float v0 = ep1[s*128+lane], v1 = ep1[s*128+64+lane];
    float sum = v0+v1, sq_ = v0*v0 + v1*v1;
    #pragma unroll
    for (int o=32;o>=1;o>>=1){ sum += __shfl_xor(sum,o); sq_ += __shfl_xor(sq_,o); }
    const float mu  = sum * 0.0078125f;
    const float var = sq_ * 0.0078125f - mu*mu;
    const float rs  = rsqrtf(var + 1e-5f);
    ep1[s*128+lane]    = (v0-mu)*rs*lng[lane]    + lnb[lane];
    ep1[s*128+64+lane] = (v1-mu)*rs*lng[64+lane] + lnb[64+lane];
  }
  __syncthreads();
  #pragma unroll
  for (int si=0; si<2; ++si){
    const int s = sh + si;
    float a = m1b[d];
    a += dot128(m1w + d*256,       ep1  + s*128);
    a += dot128(m1w + d*256 + 128, srce + s*128);
    ep2[s*128+d] = fmaxf(a, 0.f);
  }
  __syncthreads();
  #pragma unroll
  for (int si=0; si<2; ++si){
    const int s = sh + si;
    out[(size_t)(gsrc0+s)*128 + d] = m2b[d] + dot128(m2w + d*128, ep2 + s*128);
  }
}

extern "C" void kernel_launch(void* const* d_in, const int* in_sizes, int n_in,
                              void* d_out, int out_size, void* d_ws, size_t ws_size,
                              hipStream_t stream){
  const float* src = (const float*)d_in[0];
  const float* ngh = (const float*)d_in[1];
  const float* hid = (const float*)d_in[2];
  const int*   msk = (const int*)  d_in[3];
  const float* wih = (const float*)d_in[4];
  const float* whh = (const float*)d_in[5];
  const float* bih = (const float*)d_in[6];
  const float* bhh = (const float*)d_in[7];
  const float* wqs = (const float*)d_in[8];
  const float* wks = (const float*)d_in[9];
  const float* wvs = (const float*)d_in[10];
  const float* fcw = (const float*)d_in[11];
  const float* fcb = (const float*)d_in[12];
  const float* lng = (const float*)d_in[13];
  const float* lnb = (const float*)d_in[14];
  const float* m1w = (const float*)d_in[15];
  const float* m1b = (const float*)d_in[16];
  const float* m2w = (const float*)d_in[17];
  const float* m2b = (const float*)d_in[18];
  float* out = (float*)d_out;

  unsigned short* wbf   = (unsigned short*)d_ws;                   // 196608 B
  int*            flags = (int*)((char*)d_ws + 196608);            // 64 B
  float*          M_ws  = (float*)((char*)d_ws + 196672);          // 131072 B
  unsigned short* qk_ws = (unsigned short*)((char*)d_ws + 327744); // 4 MB
  unsigned long long* mask_bits = (unsigned long long*)((char*)d_ws + 4522048); // 64 KB

  hipMemsetAsync((char*)d_ws + 196608, 0, 64, stream);
  prep_all <<<7296, 256, 0, stream>>>(wih, whh, wqs, wks, wvs, fcw, src, msk, hid,
                                      wbf, M_ws, qk_ws, mask_bits, flags);
  cawn_main<<<2048, 256, 0, stream>>>(src, ngh, hid, bih, bhh,
                                      fcb, lng, lnb, m1w, m1b, m2w, m2b,
                                      wbf, wbf + 49152, M_ws, qk_ws,
                                      mask_bits, flags, out);
}